// Round 1
// baseline (1504.153 us; speedup 1.0000x reference)
//
#include <hip/hip_runtime.h>
#include <stdint.h>

#define NQ 16384
#define ND 16384
#define KNB 32                  // neighbors emitted per query
#define KK 33                   // need the 33rd-smallest (rank index 32)
#define SPLITS_BASE (NQ * KNB)  // 524288
#define PARTS 8
#define CHUNK (ND / PARTS)      // 2048
#define TILE 1024
#define BUF 32

#define FINF (__int_as_float(0x7f800000))

// Exact replication of reference arithmetic:
//   q2 = (qx*qx + qy*qy) + qz*qz                (plain rounding, left-to-right)
//   d2 = (x*x + y*y) + z*z                      (plain)
//   dot = fma(qz,z, fma(qy,y, qx*x))            (BLAS-style fma chain)
//   sq  = (q2 + d2) - (dot + dot)               (2*dot is exact)
//   dist = sqrtf(fmaxf(sq, 0))                  (correctly-rounded sqrtf)

__device__ __forceinline__ void heap_insert(float* __restrict__ arrk, int* __restrict__ arri,
                                            float key, int idx, float& cur_maxk, int& maxpos) {
    arrk[maxpos] = key; arri[maxpos] = idx;
    // rescan for new max (fixed trip: independent scratch loads pipeline well)
    float m = -1.0f; int mp = 0;
    for (int j = 0; j < KK; ++j) {
        float v = arrk[j];
        if (v > m) { m = v; mp = j; }
    }
    cur_maxk = m; maxpos = mp;
}

// --- K1: per (query, data-chunk) top-33 by clamped squared distance ---
__global__ __launch_bounds__(256) void knn_part_kernel(const float* __restrict__ data,
                                                       const float* __restrict__ queries,
                                                       float2* __restrict__ ws_pairs) {
    __shared__ float4 tile[TILE];
    const int b = blockIdx.x;
    const int part = b % PARTS;
    const int q = (b / PARTS) * 256 + threadIdx.x;

    const float qx = queries[3*q+0], qy = queries[3*q+1], qz = queries[3*q+2];
    const float q2 = __fadd_rn(__fadd_rn(__fmul_rn(qx,qx), __fmul_rn(qy,qy)), __fmul_rn(qz,qz));

    float arrk[KK]; int arri[KK];
    for (int j = 0; j < KK; ++j) { arrk[j] = FINF; arri[j] = ND; }
    float cur_maxk = FINF; int maxpos = 0;

    float bk[BUF]; int bi[BUF]; int bc = 0;

    const int base = part * CHUNK;
    for (int t0 = 0; t0 < CHUNK; t0 += TILE) {
        for (int p = threadIdx.x; p < TILE; p += 256) {
            const int g = base + t0 + p;
            const float x = data[3*g+0], y = data[3*g+1], z = data[3*g+2];
            const float d2 = __fadd_rn(__fadd_rn(__fmul_rn(x,x), __fmul_rn(y,y)), __fmul_rn(z,z));
            tile[p] = make_float4(x, y, z, d2);
        }
        __syncthreads();
        #pragma unroll 4
        for (int p = 0; p < TILE; ++p) {
            const float4 dp = tile[p];
            const float dot = __fmaf_rn(qz, dp.z, __fmaf_rn(qy, dp.y, __fmul_rn(qx, dp.x)));
            const float sq  = __fsub_rn(__fadd_rn(q2, dp.w), __fadd_rn(dot, dot));
            const float key = fmaxf(sq, 0.0f);
            if (key < cur_maxk) { bk[bc] = key; bi[bc] = base + t0 + p; ++bc; }
            if (__any(bc >= BUF)) {          // wave-synchronized flush
                #pragma unroll 1
                for (int u = 0; u < bc; ++u)
                    if (bk[u] < cur_maxk) heap_insert(arrk, arri, bk[u], bi[u], cur_maxk, maxpos);
                bc = 0;
            }
        }
        __syncthreads();
    }
    #pragma unroll 1
    for (int u = 0; u < bc; ++u)
        if (bk[u] < cur_maxk) heap_insert(arrk, arri, bk[u], bi[u], cur_maxk, maxpos);

    float2* outp = ws_pairs + (size_t)(q * PARTS + part) * KK;
    for (int j = 0; j < KK; ++j) outp[j] = make_float2(arrk[j], __int_as_float(arri[j]));
}

// --- shared finalize: k = sqrt(33rd-smallest key); accept dist<k; sort idx; write row ---
__device__ __forceinline__ void finalize_and_write(float* __restrict__ arrk, int* __restrict__ arri,
                                                   float cur_maxk, int q,
                                                   int* __restrict__ out_nb, int* __restrict__ splits) {
    const float kdist = sqrtf(cur_maxk);
    int acc[KNB]; int c = 0;
    #pragma unroll 1
    for (int j = 0; j < KK; ++j) {
        const float d = sqrtf(arrk[j]);
        if (d < kdist && c < KNB) acc[c++] = arri[j];
    }
    // insertion-sort accepted indices ascending
    #pragma unroll 1
    for (int a = 1; a < c; ++a) {
        const int v = acc[a]; int j = a;
        while (j > 0 && acc[j-1] > v) { acc[j] = acc[j-1]; --j; }
        acc[j] = v;
    }
    int* row = out_nb + (size_t)q * KNB;
    for (int j = 0; j < KNB; ++j) row[j] = (j < c) ? acc[j] : ND;
    splits[1 + q] = c;
}

// --- K2: merge the PARTS partial top-33 lists, finalize ---
__global__ __launch_bounds__(256) void knn_merge_kernel(const float2* __restrict__ ws_pairs,
                                                        int* __restrict__ out_nb,
                                                        int* __restrict__ splits) {
    const int q = blockIdx.x * 256 + threadIdx.x;
    float arrk[KK]; int arri[KK];
    for (int j = 0; j < KK; ++j) { arrk[j] = FINF; arri[j] = ND; }
    float cur_maxk = FINF; int maxpos = 0;
    const float2* src = ws_pairs + (size_t)q * PARTS * KK;
    #pragma unroll 1
    for (int e = 0; e < PARTS * KK; ++e) {
        const float2 pr = src[e];
        if (pr.x < cur_maxk) heap_insert(arrk, arri, pr.x, __float_as_int(pr.y), cur_maxk, maxpos);
    }
    finalize_and_write(arrk, arri, cur_maxk, q, out_nb, splits);
}

// --- fallback (ws too small): full scan per thread, finalize inline ---
__global__ __launch_bounds__(256) void knn_direct_kernel(const float* __restrict__ data,
                                                         const float* __restrict__ queries,
                                                         int* __restrict__ out_nb,
                                                         int* __restrict__ splits) {
    __shared__ float4 tile[TILE];
    const int q = blockIdx.x * 256 + threadIdx.x;
    const float qx = queries[3*q+0], qy = queries[3*q+1], qz = queries[3*q+2];
    const float q2 = __fadd_rn(__fadd_rn(__fmul_rn(qx,qx), __fmul_rn(qy,qy)), __fmul_rn(qz,qz));

    float arrk[KK]; int arri[KK];
    for (int j = 0; j < KK; ++j) { arrk[j] = FINF; arri[j] = ND; }
    float cur_maxk = FINF; int maxpos = 0;
    float bk[BUF]; int bi[BUF]; int bc = 0;

    for (int t0 = 0; t0 < ND; t0 += TILE) {
        for (int p = threadIdx.x; p < TILE; p += 256) {
            const int g = t0 + p;
            const float x = data[3*g+0], y = data[3*g+1], z = data[3*g+2];
            const float d2 = __fadd_rn(__fadd_rn(__fmul_rn(x,x), __fmul_rn(y,y)), __fmul_rn(z,z));
            tile[p] = make_float4(x, y, z, d2);
        }
        __syncthreads();
        #pragma unroll 4
        for (int p = 0; p < TILE; ++p) {
            const float4 dp = tile[p];
            const float dot = __fmaf_rn(qz, dp.z, __fmaf_rn(qy, dp.y, __fmul_rn(qx, dp.x)));
            const float sq  = __fsub_rn(__fadd_rn(q2, dp.w), __fadd_rn(dot, dot));
            const float key = fmaxf(sq, 0.0f);
            if (key < cur_maxk) { bk[bc] = key; bi[bc] = t0 + p; ++bc; }
            if (__any(bc >= BUF)) {
                #pragma unroll 1
                for (int u = 0; u < bc; ++u)
                    if (bk[u] < cur_maxk) heap_insert(arrk, arri, bk[u], bi[u], cur_maxk, maxpos);
                bc = 0;
            }
        }
        __syncthreads();
    }
    #pragma unroll 1
    for (int u = 0; u < bc; ++u)
        if (bk[u] < cur_maxk) heap_insert(arrk, arri, bk[u], bi[u], cur_maxk, maxpos);

    finalize_and_write(arrk, arri, cur_maxk, q, out_nb, splits);
}

// --- K3: in-place inclusive scan of counts -> splits (single block) ---
__global__ __launch_bounds__(1024) void splits_scan_kernel(int* __restrict__ splits) {
    __shared__ int lds[1024];
    const int t = threadIdx.x;
    int v[16]; int s = 0;
    #pragma unroll
    for (int j = 0; j < 16; ++j) { v[j] = splits[1 + t*16 + j]; s += v[j]; }
    lds[t] = s;
    __syncthreads();
    for (int off = 1; off < 1024; off *= 2) {
        const int add = (t >= off) ? lds[t - off] : 0;
        __syncthreads();
        lds[t] += add;
        __syncthreads();
    }
    int run = lds[t] - s;  // exclusive prefix of this thread's chunk
    #pragma unroll
    for (int j = 0; j < 16; ++j) { run += v[j]; splits[1 + t*16 + j] = run; }
    if (t == 0) splits[0] = 0;
}

extern "C" void kernel_launch(void* const* d_in, const int* in_sizes, int n_in,
                              void* d_out, int out_size, void* d_ws, size_t ws_size,
                              hipStream_t stream) {
    const float* data    = (const float*)d_in[0];
    const float* queries = (const float*)d_in[1];
    int* out    = (int*)d_out;
    int* splits = out + SPLITS_BASE;

    const size_t need = (size_t)NQ * PARTS * KK * sizeof(float2);  // ~34.6 MB
    if (ws_size >= need) {
        hipLaunchKernelGGL(knn_part_kernel, dim3(NQ/256 * PARTS), dim3(256), 0, stream,
                           data, queries, (float2*)d_ws);
        hipLaunchKernelGGL(knn_merge_kernel, dim3(NQ/256), dim3(256), 0, stream,
                           (const float2*)d_ws, out, splits);
    } else {
        hipLaunchKernelGGL(knn_direct_kernel, dim3(NQ/256), dim3(256), 0, stream,
                           data, queries, out, splits);
    }
    hipLaunchKernelGGL(splits_scan_kernel, dim3(1), dim3(1024), 0, stream, splits);
}

// Round 2
// 1059.819 us; speedup vs baseline: 1.4193x; 1.4193x over previous
//
#include <hip/hip_runtime.h>
#include <stdint.h>

typedef unsigned long long u64;
typedef unsigned int u32;

#define NQ 16384
#define ND 16384
#define KNB 32                  // neighbors emitted per query
#define KK 33                   // need the 33rd-smallest (rank index 32)
#define SPLITS_BASE (NQ * KNB)  // 524288
#define PARTS 4
#define CHUNK (ND / PARTS)      // 4096
#define NT 256
#define BUF 8

#define FINF (__int_as_float(0x7f800000))
#define PACK_INF ((((u64)0x7f800000u) << 32) | 0xffffffffu)

// Exact replication of reference arithmetic (same as passing R1 kernel):
//   q2 = (qx*qx + qy*qy) + qz*qz ; d2 likewise
//   dot = fma(qz,z, fma(qy,y, qx*x)) ; sq = (q2+d2) - (dot+dot)
//   dist = sqrtf(fmaxf(sq,0)) ; k = 33rd smallest dist ; accept dist < k

__device__ __forceinline__ float hi_f32(u64 v) { return __uint_as_float((u32)(v >> 32)); }

// Per-thread max-heap of KK packed (key,idx) u64s in LDS, node-major [node][tid].
// Node KK is a zero pad so invalid children read 0 (never the max).
// Precondition: v < root (caller checks hi_f32(v) < rootf strictly).
__device__ __forceinline__ void heap_replace_root(u64* __restrict__ h, int tid, u64 v, u64& root) {
    u64 cur = v;
    int node = 0;
    bool done = false;
    #pragma unroll
    for (int lvl = 0; lvl < 5; ++lvl) {
        const int c1 = 2 * node + 1;
        const bool valid = (lvl < 4) || (c1 <= 31);   // node 15 is the only depth-4 parent
        const int cc1 = valid ? c1 : KK;
        const int cc2 = valid ? (c1 + 1) : KK;
        const u64 h1 = h[cc1 * NT + tid];
        const u64 h2 = h[cc2 * NT + tid];
        const bool g = h1 > h2;
        const u64 big = g ? h1 : h2;
        const int bigc = g ? cc1 : cc2;
        const bool mv = (!done) && (big > cur);
        if (lvl == 0) root = mv ? big : cur;          // new h[0] value
        if (mv) h[node * NT + tid] = big;
        node = mv ? bigc : node;
        done = done || !mv;
        if (lvl >= 1 && __all(done)) break;           // wave-uniform early exit
    }
    h[node * NT + tid] = cur;
}

// --- K0: pack points as (x,y,z,d2) ---
__global__ __launch_bounds__(256) void build_pts(const float* __restrict__ data,
                                                 float4* __restrict__ pts) {
    const int i = blockIdx.x * 256 + threadIdx.x;
    const float x = data[3*i], y = data[3*i+1], z = data[3*i+2];
    const float d2 = __fadd_rn(__fadd_rn(__fmul_rn(x,x), __fmul_rn(y,y)), __fmul_rn(z,z));
    pts[i] = make_float4(x, y, z, d2);
}

// --- K1: per (query, part) top-33 into LDS heap; dump to ws pairs[part][j][q] ---
__global__ __launch_bounds__(NT) void knn_part(const float4* __restrict__ pts,
                                               const float* __restrict__ queries,
                                               u64* __restrict__ pairs) {
    extern __shared__ u64 smem[];
    u64* heap = smem;                    // (KK+1)*NT
    u64* buf  = smem + (KK + 1) * NT;    // BUF*NT
    const int tid = threadIdx.x;
    const int b = blockIdx.x;
    const int part = b & (PARTS - 1);
    const int q = (b >> 2) * NT + tid;

    const float qx = queries[3*q], qy = queries[3*q+1], qz = queries[3*q+2];
    const float q2 = __fadd_rn(__fadd_rn(__fmul_rn(qx,qx), __fmul_rn(qy,qy)), __fmul_rn(qz,qz));

    #pragma unroll
    for (int j = 0; j < KK; ++j) heap[j * NT + tid] = PACK_INF;
    heap[KK * NT + tid] = 0;             // pad
    u64 root = PACK_INF;
    float rootf = FINF;

    int bc = 0;
    const int base = part * CHUNK;
    for (int p0 = 0; p0 < CHUNK; p0 += 4) {
        #pragma unroll
        for (int u = 0; u < 4; ++u) {
            const int g = base + p0 + u;
            const float4 w = pts[g];     // wave-uniform address -> scalar/broadcast load
            const float dot = __fmaf_rn(qz, w.z, __fmaf_rn(qy, w.y, __fmul_rn(qx, w.x)));
            const float sq  = __fsub_rn(__fadd_rn(q2, w.w), __fadd_rn(dot, dot));
            if (sq < rootf) {            // strict; == max(sq,0) < rootf (rootf >= 0 or inf)
                const float key = fmaxf(sq, 0.0f);
                buf[bc * NT + tid] = (((u64)__float_as_uint(key)) << 32) | (u32)g;
                ++bc;
            }
        }
        if (__any(bc >= BUF - 3)) {
            for (int u = 0; u < BUF; ++u) {
                if (u < bc) {
                    const u64 v = buf[u * NT + tid];
                    if (hi_f32(v) < rootf) {  // re-check vs tightened threshold
                        heap_replace_root(heap, tid, v, root);
                        rootf = hi_f32(root);
                    }
                }
            }
            bc = 0;
        }
    }
    for (int u = 0; u < BUF; ++u) {      // final flush
        if (u < bc) {
            const u64 v = buf[u * NT + tid];
            if (hi_f32(v) < rootf) { heap_replace_root(heap, tid, v, root); rootf = hi_f32(root); }
        }
    }
    #pragma unroll
    for (int j = 0; j < KK; ++j)
        pairs[(size_t)(part * KK + j) * NQ + q] = heap[j * NT + tid];  // coalesced
}

// --- K2: merge PARTS*33 candidates per query via the same LDS heap; finalize ---
__global__ __launch_bounds__(NT) void knn_merge(const u64* __restrict__ pairs,
                                                int* __restrict__ out_nb,
                                                int* __restrict__ splits) {
    extern __shared__ u64 smem[];
    u64* heap = smem;                        // (KK+1)*NT
    int* srt  = (int*)(smem + (KK + 1) * NT); // KNB*NT
    const int tid = threadIdx.x;
    const int q = blockIdx.x * NT + tid;

    #pragma unroll
    for (int j = 0; j < KK; ++j) heap[j * NT + tid] = PACK_INF;
    heap[KK * NT + tid] = 0;
    u64 root = PACK_INF;
    float rootf = FINF;

    #pragma unroll 1
    for (int e = 0; e < PARTS * KK; ++e) {
        const u64 v = pairs[(size_t)e * NQ + q];  // coalesced across lanes
        if (hi_f32(v) < rootf) { heap_replace_root(heap, tid, v, root); rootf = hi_f32(root); }
    }

    const float kdist = sqrtf(rootf);   // k = 33rd smallest dist (root of merged heap)
    int c = 0;
    #pragma unroll 1
    for (int j = 0; j < KK; ++j) {
        const u64 v = heap[j * NT + tid];
        const float d = sqrtf(hi_f32(v));
        if (d < kdist && c < KNB) {     // reference semantics: dist < k (post-sqrt compare)
            const int idx = (int)(u32)(v & 0xffffffffu);
            int t = c;
            while (t > 0 && srt[(t-1) * NT + tid] > idx) { srt[t * NT + tid] = srt[(t-1) * NT + tid]; --t; }
            srt[t * NT + tid] = idx;
            ++c;
        }
    }
    int* row = out_nb + (size_t)q * KNB;
    for (int j = 0; j < KNB; ++j) row[j] = (j < c) ? srt[j * NT + tid] : ND;
    splits[1 + q] = c;
}

// --- fallback (ws too small): R1's direct kernel, unchanged (correct, slow) ---
__global__ __launch_bounds__(256) void knn_direct_kernel(const float* __restrict__ data,
                                                         const float* __restrict__ queries,
                                                         int* __restrict__ out_nb,
                                                         int* __restrict__ splits) {
    __shared__ float4 tile[1024];
    const int q = blockIdx.x * 256 + threadIdx.x;
    const float qx = queries[3*q], qy = queries[3*q+1], qz = queries[3*q+2];
    const float q2 = __fadd_rn(__fadd_rn(__fmul_rn(qx,qx), __fmul_rn(qy,qy)), __fmul_rn(qz,qz));
    float arrk[KK]; int arri[KK];
    for (int j = 0; j < KK; ++j) { arrk[j] = FINF; arri[j] = ND; }
    float cur_maxk = FINF;
    for (int t0 = 0; t0 < ND; t0 += 1024) {
        for (int p = threadIdx.x; p < 1024; p += 256) {
            const int g = t0 + p;
            const float x = data[3*g], y = data[3*g+1], z = data[3*g+2];
            const float d2 = __fadd_rn(__fadd_rn(__fmul_rn(x,x), __fmul_rn(y,y)), __fmul_rn(z,z));
            tile[p] = make_float4(x, y, z, d2);
        }
        __syncthreads();
        for (int p = 0; p < 1024; ++p) {
            const float4 dp = tile[p];
            const float dot = __fmaf_rn(qz, dp.z, __fmaf_rn(qy, dp.y, __fmul_rn(qx, dp.x)));
            const float sq  = __fsub_rn(__fadd_rn(q2, dp.w), __fadd_rn(dot, dot));
            const float key = fmaxf(sq, 0.0f);
            if (key < cur_maxk) {
                int mp = 0; float m = -1.0f;
                for (int j = 0; j < KK; ++j) if (arrk[j] > m) { m = arrk[j]; mp = j; }
                arrk[mp] = key; arri[mp] = t0 + p;
                m = -1.0f;
                for (int j = 0; j < KK; ++j) if (arrk[j] > m) m = arrk[j];
                cur_maxk = m;
            }
        }
        __syncthreads();
    }
    const float kdist = sqrtf(cur_maxk);
    int acc[KNB]; int c = 0;
    for (int j = 0; j < KK; ++j) {
        const float d = sqrtf(arrk[j]);
        if (d < kdist && c < KNB) acc[c++] = arri[j];
    }
    for (int a = 1; a < c; ++a) {
        const int v = acc[a]; int j = a;
        while (j > 0 && acc[j-1] > v) { acc[j] = acc[j-1]; --j; }
        acc[j] = v;
    }
    int* row = out_nb + (size_t)q * KNB;
    for (int j = 0; j < KNB; ++j) row[j] = (j < c) ? acc[j] : ND;
    splits[1 + q] = c;
}

// --- K3: in-place scan of counts -> splits (single block) ---
__global__ __launch_bounds__(1024) void splits_scan_kernel(int* __restrict__ splits) {
    __shared__ int lds[1024];
    const int t = threadIdx.x;
    int v[16]; int s = 0;
    #pragma unroll
    for (int j = 0; j < 16; ++j) { v[j] = splits[1 + t*16 + j]; s += v[j]; }
    lds[t] = s;
    __syncthreads();
    for (int off = 1; off < 1024; off *= 2) {
        const int add = (t >= off) ? lds[t - off] : 0;
        __syncthreads();
        lds[t] += add;
        __syncthreads();
    }
    int run = lds[t] - s;
    #pragma unroll
    for (int j = 0; j < 16; ++j) { run += v[j]; splits[1 + t*16 + j] = run; }
    if (t == 0) splits[0] = 0;
}

extern "C" void kernel_launch(void* const* d_in, const int* in_sizes, int n_in,
                              void* d_out, int out_size, void* d_ws, size_t ws_size,
                              hipStream_t stream) {
    const float* data    = (const float*)d_in[0];
    const float* queries = (const float*)d_in[1];
    int* out    = (int*)d_out;
    int* splits = out + SPLITS_BASE;

    const size_t pts_bytes  = (size_t)ND * sizeof(float4);                 // 256 KB
    const size_t pair_bytes = (size_t)PARTS * KK * NQ * sizeof(u64);       // ~17.3 MB
    const size_t need = pts_bytes + pair_bytes;

    if (ws_size >= need) {
        float4* pts = (float4*)d_ws;
        u64* pairs  = (u64*)((char*)d_ws + pts_bytes);

        const int smem1 = (KK + 1) * NT * sizeof(u64) + BUF * NT * sizeof(u64);   // 86016 B
        const int smem2 = (KK + 1) * NT * sizeof(u64) + KNB * NT * sizeof(int);   // 102400 B
        hipFuncSetAttribute((const void*)knn_part,  hipFuncAttributeMaxDynamicSharedMemorySize, smem1);
        hipFuncSetAttribute((const void*)knn_merge, hipFuncAttributeMaxDynamicSharedMemorySize, smem2);

        hipLaunchKernelGGL(build_pts, dim3(ND/256), dim3(256), 0, stream, data, pts);
        hipLaunchKernelGGL(knn_part, dim3((NQ/NT) * PARTS), dim3(NT), smem1, stream,
                           pts, queries, pairs);
        hipLaunchKernelGGL(knn_merge, dim3(NQ/NT), dim3(NT), smem2, stream,
                           pairs, out, splits);
    } else {
        hipLaunchKernelGGL(knn_direct_kernel, dim3(NQ/256), dim3(256), 0, stream,
                           data, queries, out, splits);
    }
    hipLaunchKernelGGL(splits_scan_kernel, dim3(1), dim3(1024), 0, stream, splits);
}

// Round 3
// 657.353 us; speedup vs baseline: 2.2882x; 1.6123x over previous
//
#include <hip/hip_runtime.h>
#include <stdint.h>

typedef unsigned int u32;

#define NQ 16384
#define ND 16384
#define KNB 32                  // neighbors emitted per query
#define KK 33                   // need the 33rd-smallest (rank index 32)
#define SPLITS_BASE (NQ * KNB)  // 524288
#define PARTS 8
#define CHUNK (ND / PARTS)      // 2048
#define NT 256
#define SEED 64

#define FINF (__int_as_float(0x7f800000))

// Exact replication of reference arithmetic (same as passing R1/R2 kernels):
//   q2 = (qx*qx + qy*qy) + qz*qz ; d2 likewise
//   dot = fma(qz,z, fma(qy,y, qx*x)) ; sq = (q2+d2) - (dot+dot)
//   dist = sqrtf(fmaxf(sq,0)) ; k = 33rd smallest dist ; accept dist < k

// Insert key into descending-sorted a[0..KK-1], dropping current max a[0].
// Precondition: key < a[0]. Branch-free, static indexing, ILP across j.
__device__ __forceinline__ void tins(float* __restrict__ a, float key) {
    #pragma unroll
    for (int j = 0; j < KK - 1; ++j)
        a[j] = fmaxf(a[j + 1], fminf(a[j], key));
    a[KK - 1] = fminf(a[KK - 1], key);
}

#define DIST_SQ(g, sq)                                                              \
    float sq;                                                                       \
    {                                                                               \
        const float x = data[3*(g)], y = data[3*(g)+1], z = data[3*(g)+2];          \
        const float d2 = __fadd_rn(__fadd_rn(__fmul_rn(x,x), __fmul_rn(y,y)),       \
                                   __fmul_rn(z,z));                                 \
        const float dot = __fmaf_rn(qz, z, __fmaf_rn(qy, y, __fmul_rn(qx, x)));     \
        sq = __fsub_rn(__fadd_rn(q2, d2), __fadd_rn(dot, dot));                     \
    }

// --- K1: per (query, part) top-33 KEYS (clamped sq domain) in registers ---
__global__ __launch_bounds__(NT) void part_thresh(const float* __restrict__ data,
                                                  const float* __restrict__ queries,
                                                  float* __restrict__ thr) {
    const int tid = threadIdx.x;
    const int part = blockIdx.x & (PARTS - 1);
    const int q = (blockIdx.x >> 3) * NT + tid;

    const float qx = queries[3*q], qy = queries[3*q+1], qz = queries[3*q+2];
    const float q2 = __fadd_rn(__fadd_rn(__fmul_rn(qx,qx), __fmul_rn(qy,qy)), __fmul_rn(qz,qz));

    float a[KK];
    #pragma unroll
    for (int j = 0; j < KK; ++j) a[j] = FINF;

    const int base = part * CHUNK;

    // Phase 1: seed with the first SEED points, direct insert (accept rate ~1 anyway)
    #pragma unroll 1
    for (int t = 0; t < SEED; ++t) {
        DIST_SQ(base + t, sq)
        const float key = fmaxf(sq, 0.0f);
        if (key < a[0]) tins(a, key);
    }

    // Phase 2: buffered. Register shift-buffer depth 8; trigger at cnt>=5 every
    // 4 points => cnt <= 8 at all times (no candidate loss).
    float b0=0,b1=0,b2=0,b3=0,b4=0,b5=0,b6=0,b7=0;
    int cnt = 0;
    #pragma unroll 1
    for (int p0 = SEED; p0 < CHUNK; p0 += 4) {
        #pragma unroll
        for (int u = 0; u < 4; ++u) {
            DIST_SQ(base + p0 + u, sq)
            const bool acc = sq < a[0];
            const float key = fmaxf(sq, 0.0f);
            b7 = acc ? b6 : b7;  b6 = acc ? b5 : b6;
            b5 = acc ? b4 : b5;  b4 = acc ? b3 : b4;
            b3 = acc ? b2 : b3;  b2 = acc ? b1 : b2;
            b1 = acc ? b0 : b1;  b0 = acc ? key : b0;
            cnt += acc;
        }
        if (__any(cnt >= 5)) {
            if (cnt > 0 && b0 < a[0]) tins(a, b0);
            if (cnt > 1 && b1 < a[0]) tins(a, b1);
            if (cnt > 2 && b2 < a[0]) tins(a, b2);
            if (cnt > 3 && b3 < a[0]) tins(a, b3);
            if (cnt > 4 && b4 < a[0]) tins(a, b4);
            if (cnt > 5 && b5 < a[0]) tins(a, b5);
            if (cnt > 6 && b6 < a[0]) tins(a, b6);
            if (cnt > 7 && b7 < a[0]) tins(a, b7);
            cnt = 0;
        }
    }
    if (cnt > 0 && b0 < a[0]) tins(a, b0);
    if (cnt > 1 && b1 < a[0]) tins(a, b1);
    if (cnt > 2 && b2 < a[0]) tins(a, b2);
    if (cnt > 3 && b3 < a[0]) tins(a, b3);
    if (cnt > 4 && b4 < a[0]) tins(a, b4);
    if (cnt > 5 && b5 < a[0]) tins(a, b5);
    if (cnt > 6 && b6 < a[0]) tins(a, b6);
    if (cnt > 7 && b7 < a[0]) tins(a, b7);

    #pragma unroll
    for (int j = 0; j < KK; ++j)
        thr[(size_t)(part * KK + j) * NQ + q] = a[j];   // coalesced
}

// --- K2: merge 8x33 keys -> exact 33rd key -> sqrt-domain cut per query ---
__global__ __launch_bounds__(NT) void merge_cut(const float* __restrict__ thr,
                                                float* __restrict__ cut) {
    const int q = blockIdx.x * NT + threadIdx.x;
    float a[KK];
    #pragma unroll
    for (int j = 0; j < KK; ++j) a[j] = FINF;
    #pragma unroll 1
    for (int e = 0; e < PARTS * KK; ++e) {
        const float v = thr[(size_t)e * NQ + q];
        if (v < a[0]) tins(a, v);
    }
    const float k33 = a[0];            // exact 33rd-smallest clamped sq key
    const float kd = sqrtf(k33);       // reference k (fp32 sqrt)
    float c;
    if (!(kd > 0.0f)) {
        c = -1.0f;                     // accept nothing (ref: dist < 0 impossible)
    } else {
        // c = min{x >= 0 : sqrtf(x) >= kd}; boundary within ~2 ulp of kd*kd
        int bi = __float_as_int(__fmul_rn(kd, kd));
        #pragma unroll 1
        for (int s = 0; s < 8; ++s) {
            if (bi > 0 && sqrtf(__int_as_float(bi - 1)) >= kd) --bi; else break;
        }
        #pragma unroll 1
        for (int s = 0; s < 8; ++s) {
            if (sqrtf(__int_as_float(bi)) < kd) ++bi; else break;
        }
        c = __int_as_float(bi);
    }
    cut[q] = c;                        // key < c  <=>  sqrtf(key) < kd
}

// --- K3: rescan; compact accepted indices per (query, part) ---
__global__ __launch_bounds__(NT) void collect(const float* __restrict__ data,
                                              const float* __restrict__ queries,
                                              const float* __restrict__ cut,
                                              u32* __restrict__ plist,
                                              u32* __restrict__ cnt) {
    const int tid = threadIdx.x;
    const int part = blockIdx.x & (PARTS - 1);
    const int q = (blockIdx.x >> 3) * NT + tid;

    const float qx = queries[3*q], qy = queries[3*q+1], qz = queries[3*q+2];
    const float q2 = __fadd_rn(__fadd_rn(__fmul_rn(qx,qx), __fmul_rn(qy,qy)), __fmul_rn(qz,qz));
    const float c = cut[q];
    const int base = part * CHUNK;

    int slot = 0;
    #pragma unroll 4
    for (int t = 0; t < CHUNK; ++t) {
        const int g = base + t;
        DIST_SQ(g, sq)
        if (fmaxf(sq, 0.0f) < c) {     // == (dist < k), proven <= 32 per query
            if (slot < KNB) plist[(size_t)(part * KNB + slot) * NQ + q] = (u32)g;
            ++slot;
        }
    }
    cnt[part * NQ + q] = (slot < KNB) ? slot : KNB;
}

// --- K4: concatenate part lists (already ascending), pad, write counts ---
__global__ __launch_bounds__(NT) void emit(const u32* __restrict__ plist,
                                           const u32* __restrict__ cnt,
                                           int* __restrict__ out_nb,
                                           int* __restrict__ splits) {
    const int q = blockIdx.x * NT + threadIdx.x;
    int total = 0;
    #pragma unroll 1
    for (int p = 0; p < PARTS; ++p) {
        const int k = (int)cnt[p * NQ + q];
        #pragma unroll 1
        for (int j = 0; j < k; ++j) {
            if (total < KNB)
                out_nb[(size_t)q * KNB + total] = (int)plist[(size_t)(p * KNB + j) * NQ + q];
            ++total;
        }
    }
    const int tt = (total < KNB) ? total : KNB;
    for (int j = tt; j < KNB; ++j) out_nb[(size_t)q * KNB + j] = ND;
    splits[1 + q] = tt;
}

// --- fallback (ws too small): direct per-thread scan (correct, slow) ---
__global__ __launch_bounds__(256) void knn_direct_kernel(const float* __restrict__ data,
                                                         const float* __restrict__ queries,
                                                         int* __restrict__ out_nb,
                                                         int* __restrict__ splits) {
    __shared__ float4 tile[1024];
    const int q = blockIdx.x * 256 + threadIdx.x;
    const float qx = queries[3*q], qy = queries[3*q+1], qz = queries[3*q+2];
    const float q2 = __fadd_rn(__fadd_rn(__fmul_rn(qx,qx), __fmul_rn(qy,qy)), __fmul_rn(qz,qz));
    float arrk[KK]; int arri[KK];
    for (int j = 0; j < KK; ++j) { arrk[j] = FINF; arri[j] = ND; }
    float cur_maxk = FINF;
    for (int t0 = 0; t0 < ND; t0 += 1024) {
        for (int p = threadIdx.x; p < 1024; p += 256) {
            const int g = t0 + p;
            const float x = data[3*g], y = data[3*g+1], z = data[3*g+2];
            const float d2 = __fadd_rn(__fadd_rn(__fmul_rn(x,x), __fmul_rn(y,y)), __fmul_rn(z,z));
            tile[p] = make_float4(x, y, z, d2);
        }
        __syncthreads();
        for (int p = 0; p < 1024; ++p) {
            const float4 dp = tile[p];
            const float dot = __fmaf_rn(qz, dp.z, __fmaf_rn(qy, dp.y, __fmul_rn(qx, dp.x)));
            const float sq  = __fsub_rn(__fadd_rn(q2, dp.w), __fadd_rn(dot, dot));
            const float key = fmaxf(sq, 0.0f);
            if (key < cur_maxk) {
                int mp = 0; float m = -1.0f;
                for (int j = 0; j < KK; ++j) if (arrk[j] > m) { m = arrk[j]; mp = j; }
                arrk[mp] = key; arri[mp] = t0 + p;
                m = -1.0f;
                for (int j = 0; j < KK; ++j) if (arrk[j] > m) m = arrk[j];
                cur_maxk = m;
            }
        }
        __syncthreads();
    }
    const float kdist = sqrtf(cur_maxk);
    int acc[KNB]; int c = 0;
    for (int j = 0; j < KK; ++j) {
        const float d = sqrtf(arrk[j]);
        if (d < kdist && c < KNB) acc[c++] = arri[j];
    }
    for (int a = 1; a < c; ++a) {
        const int v = acc[a]; int j = a;
        while (j > 0 && acc[j-1] > v) { acc[j] = acc[j-1]; --j; }
        acc[j] = v;
    }
    int* row = out_nb + (size_t)q * KNB;
    for (int j = 0; j < KNB; ++j) row[j] = (j < c) ? acc[j] : ND;
    splits[1 + q] = c;
}

// --- K5: in-place scan of counts -> splits (single block) ---
__global__ __launch_bounds__(1024) void splits_scan_kernel(int* __restrict__ splits) {
    __shared__ int lds[1024];
    const int t = threadIdx.x;
    int v[16]; int s = 0;
    #pragma unroll
    for (int j = 0; j < 16; ++j) { v[j] = splits[1 + t*16 + j]; s += v[j]; }
    lds[t] = s;
    __syncthreads();
    for (int off = 1; off < 1024; off *= 2) {
        const int add = (t >= off) ? lds[t - off] : 0;
        __syncthreads();
        lds[t] += add;
        __syncthreads();
    }
    int run = lds[t] - s;
    #pragma unroll
    for (int j = 0; j < 16; ++j) { run += v[j]; splits[1 + t*16 + j] = run; }
    if (t == 0) splits[0] = 0;
}

extern "C" void kernel_launch(void* const* d_in, const int* in_sizes, int n_in,
                              void* d_out, int out_size, void* d_ws, size_t ws_size,
                              hipStream_t stream) {
    const float* data    = (const float*)d_in[0];
    const float* queries = (const float*)d_in[1];
    int* out    = (int*)d_out;
    int* splits = out + SPLITS_BASE;

    // ws layout:
    //   [0, 64K):            float cut[NQ]
    //   [64K, 64K+17.3M):    float thr[PARTS][KK][NQ]   (K1 write, K2 read)
    //     reused after K2:   u32 plist[PARTS][KNB][NQ] (16.78M) + u32 cnt[PARTS][NQ] (512K)
    const size_t cut_bytes   = (size_t)NQ * sizeof(float);                       // 64 KB
    const size_t thr_bytes   = (size_t)PARTS * KK * NQ * sizeof(float);          // 17,301,504
    const size_t plist_bytes = (size_t)PARTS * KNB * NQ * sizeof(u32);           // 16,777,216
    const size_t cnt_bytes   = (size_t)PARTS * NQ * sizeof(u32);                 // 524,288
    const size_t reuse_bytes = (plist_bytes + cnt_bytes > thr_bytes) ? (plist_bytes + cnt_bytes) : thr_bytes;
    const size_t need = cut_bytes + reuse_bytes;                                 // 17,367,040

    if (ws_size >= need) {
        float* cut  = (float*)d_ws;
        float* thr  = (float*)((char*)d_ws + cut_bytes);
        u32*  plist = (u32*)((char*)d_ws + cut_bytes);
        u32*  cntp  = (u32*)((char*)d_ws + cut_bytes + plist_bytes);

        hipLaunchKernelGGL(part_thresh, dim3((NQ/NT) * PARTS), dim3(NT), 0, stream,
                           data, queries, thr);
        hipLaunchKernelGGL(merge_cut, dim3(NQ/NT), dim3(NT), 0, stream, thr, cut);
        hipLaunchKernelGGL(collect, dim3((NQ/NT) * PARTS), dim3(NT), 0, stream,
                           data, queries, cut, plist, cntp);
        hipLaunchKernelGGL(emit, dim3(NQ/NT), dim3(NT), 0, stream,
                           plist, cntp, out, splits);
    } else {
        hipLaunchKernelGGL(knn_direct_kernel, dim3(NQ/256), dim3(256), 0, stream,
                           data, queries, out, splits);
    }
    hipLaunchKernelGGL(splits_scan_kernel, dim3(1), dim3(1024), 0, stream, splits);
}

// Round 4
// 225.104 us; speedup vs baseline: 6.6820x; 2.9202x over previous
//
#include <hip/hip_runtime.h>
#include <stdint.h>

typedef unsigned long long u64;
typedef unsigned int u32;

#define NQ 16384
#define ND 16384
#define KNB 32                  // neighbors emitted per query
#define KK 33                   // need the 33rd-smallest (rank index 32)
#define SPLITS_BASE (NQ * KNB)  // 524288
#define CAP 768                 // LDS candidate pool per query
#define NWQ 4                   // queries (waves) per block
#define FINF (__int_as_float(0x7f800000))

// Exact replication of reference arithmetic (same as passing R1-R3 kernels):
//   q2 = (qx*qx + qy*qy) + qz*qz ; d2 likewise (precomputed per point)
//   dot = fma(qz,z, fma(qy,y, qx*x)) ; sq = (q2+d2) - (dot+dot)
//   key = fmaxf(sq,0) ; k = sqrtf(33rd smallest key) ; accept sqrtf(key) < k
//   via precomputed cut: key < cut  <=>  sqrtf(key) < k

__device__ __forceinline__ float wave_max_f(float v) {
    #pragma unroll
    for (int s = 1; s < 64; s <<= 1) v = fmaxf(v, __shfl_xor(v, s, 64));
    return v;
}
__device__ __forceinline__ int wave_sum_i(int v) {
    #pragma unroll
    for (int s = 1; s < 64; s <<= 1) v += __shfl_xor(v, s, 64);
    return v;
}

// min b (float bits) with #{r <= float(b)} >= rank, over the wave's NR-strided regs.
// Keys are >= 0 so float order == unsigned-bits order. Pads must be FINF.
template<int NR>
__device__ __forceinline__ float bisect_rank(const float (&r)[NR], int rank) {
    u32 lo = 0u, hi = 0x7f800000u;
    #pragma unroll 1
    while (lo < hi) {
        const u32 mid = (lo + hi) >> 1;
        const float pv = __uint_as_float(mid);
        int c = 0;
        #pragma unroll
        for (int j = 0; j < NR; ++j) c += (r[j] <= pv) ? 1 : 0;
        c = wave_sum_i(c);
        if (c >= rank) hi = mid; else lo = mid + 1;
    }
    return __uint_as_float(hi);
}

// Cheap prune: M = wave_max(per-lane min) >= pool's 33rd smallest (>= 64 elems <= M).
// Keep key <= M (multiset-safe, non-strict). In-place compaction is hazard-free:
// group j0 writes slots <= j0+63, reads of later groups are >= j0+64.
__device__ __forceinline__ void pool_prune(float* kp, u32* ip, int& cnt, float& Tk,
                                           int lane, u64 lt) {
    float m = FINF;
    #pragma unroll 1
    for (int j = lane; j < cnt; j += 64) m = fminf(m, kp[j]);
    const float M = wave_max_f(m);
    int nc = 0;
    #pragma unroll 1
    for (int j0 = 0; j0 < cnt; j0 += 64) {
        const int j = j0 + lane;
        const bool val = j < cnt;
        float k = FINF; u32 id = 0;
        if (val) { k = kp[j]; id = ip[j]; }
        const bool keep = val && (k <= M);
        const u64 mask = __ballot(keep);
        if (keep) {
            const int s = nc + (int)__popcll(mask & lt);
            kp[s] = k; ip[s] = id;
        }
        nc += (int)__popcll(mask);
    }
    cnt = nc; Tk = M;
}

// Rare/degenerate path: exact 64th-smallest via bisection; keep key < v plus at most
// 64 copies of key == v. Hard bound: cnt <= 63 + 64 = 127 afterward. Preserves the
// top-33 multiset and every key < cut (cut <= k33 <= v).
__device__ __forceinline__ void pool_hard_prune(float* kp, u32* ip, int& cnt,
                                                int lane, u64 lt) {
    float r[12];
    #pragma unroll
    for (int j = 0; j < 12; ++j) {
        const int s = j * 64 + lane;
        r[j] = (s < cnt) ? kp[s] : FINF;
    }
    const float v = bisect_rank(r, 64);
    int nc = 0, eqs = 0;
    #pragma unroll 1
    for (int j0 = 0; j0 < cnt; j0 += 64) {
        const int j = j0 + lane;
        const bool val = j < cnt;
        float k = FINF; u32 id = 0;
        if (val) { k = kp[j]; id = ip[j]; }
        const bool lt_v = val && (k < v);
        const bool eq_v = val && (k == v);
        const u64 mlt = __ballot(lt_v);
        const u64 meq = __ballot(eq_v);
        const int poplt = (int)__popcll(mlt);
        const int popeq = (int)__popcll(meq);
        if (lt_v) { const int s = nc + (int)__popcll(mlt & lt); kp[s] = k; ip[s] = id; }
        if (eq_v) {
            const int pe = (int)__popcll(meq & lt);
            if (eqs + pe < 64) { const int s = nc + poplt + pe; kp[s] = k; ip[s] = id; }
        }
        int kept_eq = popeq;
        if (eqs + popeq > 64) kept_eq = (64 - eqs > 0) ? (64 - eqs) : 0;
        nc += poplt + kept_eq;
        eqs += popeq;
    }
    cnt = nc;
}

// --- K0: pack points as (x,y,z,d2) ---
__global__ __launch_bounds__(256) void build_pts(const float* __restrict__ data,
                                                 float4* __restrict__ pts) {
    const int i = blockIdx.x * 256 + threadIdx.x;
    const float x = data[3*i], y = data[3*i+1], z = data[3*i+2];
    const float d2 = __fadd_rn(__fadd_rn(__fmul_rn(x,x), __fmul_rn(y,y)), __fmul_rn(z,z));
    pts[i] = make_float4(x, y, z, d2);
}

// --- K1: one wave per query does everything: scan+select+cut+emit ---
__global__ __launch_bounds__(256) void knn_wave(const float4* __restrict__ pts,
                                                const float* __restrict__ queries,
                                                int* __restrict__ out_nb,
                                                int* __restrict__ splits) {
    __shared__ float keyP[NWQ][CAP];
    __shared__ u32   idxP[NWQ][CAP];
    __shared__ int   accI[NWQ][KNB];

    const int lane = threadIdx.x & 63;
    const int wid  = threadIdx.x >> 6;
    const int q = blockIdx.x * NWQ + wid;
    const u64 lt = (1ull << lane) - 1ull;
    float* kp = keyP[wid];
    u32*   ip = idxP[wid];

    const float qx = queries[3*q], qy = queries[3*q+1], qz = queries[3*q+2];
    const float q2 = __fadd_rn(__fadd_rn(__fmul_rn(qx,qx), __fmul_rn(qy,qy)), __fmul_rn(qz,qz));

    float Tk = FINF;   // running upper bound on the global 33rd key (wave-uniform)
    int cnt = 0;       // pool count (wave-uniform)

    #pragma unroll 1
    for (int p0 = 0; p0 < ND; p0 += 128) {
        const float4 w0 = pts[p0 + lane];
        const float4 w1 = pts[p0 + 64 + lane];

        #pragma unroll
        for (int half = 0; half < 2; ++half) {
            const float4 w = half ? w1 : w0;
            const int idx = p0 + half * 64 + lane;
            const float dot = __fmaf_rn(qz, w.z, __fmaf_rn(qy, w.y, __fmul_rn(qx, w.x)));
            const float sq  = __fsub_rn(__fadd_rn(q2, w.w), __fadd_rn(dot, dot));
            const float key = fmaxf(sq, 0.0f);
            const bool acc = key <= Tk;
            const u64 mask = __ballot(acc);
            if (mask) {
                if (acc) {
                    const int s = cnt + (int)__popcll(mask & lt);
                    kp[s] = key; ip[s] = (u32)idx;
                }
                cnt += (int)__popcll(mask);
                if (cnt > CAP - 64) {
                    pool_prune(kp, ip, cnt, Tk, lane, lt);
                    if (cnt > CAP - 64) pool_hard_prune(kp, ip, cnt, lane, lt);
                }
            }
        }
    }

    // exact 33rd smallest key from the pool (pool provably contains top-33 multiset)
    float r[12];
    #pragma unroll
    for (int j = 0; j < 12; ++j) {
        const int s = j * 64 + lane;
        r[j] = (s < cnt) ? kp[s] : FINF;
    }
    const float k33 = bisect_rank(r, KK);

    // sqrt-domain cut (identical to R3's validated logic): key < cut <=> sqrtf(key) < kd
    const float kd = sqrtf(k33);
    float cut;
    if (!(kd > 0.0f)) {
        cut = -1.0f;
    } else {
        int bi = __float_as_int(__fmul_rn(kd, kd));
        #pragma unroll 1
        for (int s = 0; s < 8; ++s) {
            if (bi > 0 && sqrtf(__int_as_float(bi - 1)) >= kd) --bi; else break;
        }
        #pragma unroll 1
        for (int s = 0; s < 8; ++s) {
            if (sqrtf(__int_as_float(bi)) < kd) ++bi; else break;
        }
        cut = __int_as_float(bi);
    }

    // filter pool by key < cut (<= 32 survivors, globally complete), compact to accI
    int c = 0;
    #pragma unroll 1
    for (int j0 = 0; j0 < cnt; j0 += 64) {
        const int j = j0 + lane;
        const bool val = j < cnt;
        const float k = val ? kp[j] : FINF;
        const bool keep = val && (k < cut);
        const u64 mask = __ballot(keep);
        if (keep) {
            const int s = c + (int)__popcll(mask & lt);
            if (s < KNB) accI[wid][s] = (int)ip[j];
        }
        c += (int)__popcll(mask);
    }
    if (c > KNB) c = KNB;   // provably impossible; safety only

    // ranking sort by index ascending + padded row write
    if (lane < KNB) {
        if (lane < c) {
            const int my = accI[wid][lane];
            int rank = 0;
            #pragma unroll 1
            for (int j = 0; j < KNB; ++j)
                if (j < c) rank += (accI[wid][j] < my) ? 1 : 0;
            out_nb[(size_t)q * KNB + rank] = my;
        } else {
            out_nb[(size_t)q * KNB + lane] = ND;
        }
    }
    if (lane == 0) splits[1 + q] = c;
}

// --- fallback (ws too small): direct per-thread scan (correct, slow) ---
__global__ __launch_bounds__(256) void knn_direct_kernel(const float* __restrict__ data,
                                                         const float* __restrict__ queries,
                                                         int* __restrict__ out_nb,
                                                         int* __restrict__ splits) {
    __shared__ float4 tile[1024];
    const int q = blockIdx.x * 256 + threadIdx.x;
    const float qx = queries[3*q], qy = queries[3*q+1], qz = queries[3*q+2];
    const float q2 = __fadd_rn(__fadd_rn(__fmul_rn(qx,qx), __fmul_rn(qy,qy)), __fmul_rn(qz,qz));
    float arrk[KK]; int arri[KK];
    for (int j = 0; j < KK; ++j) { arrk[j] = FINF; arri[j] = ND; }
    float cur_maxk = FINF;
    for (int t0 = 0; t0 < ND; t0 += 1024) {
        for (int p = threadIdx.x; p < 1024; p += 256) {
            const int g = t0 + p;
            const float x = data[3*g], y = data[3*g+1], z = data[3*g+2];
            const float d2 = __fadd_rn(__fadd_rn(__fmul_rn(x,x), __fmul_rn(y,y)), __fmul_rn(z,z));
            tile[p] = make_float4(x, y, z, d2);
        }
        __syncthreads();
        for (int p = 0; p < 1024; ++p) {
            const float4 dp = tile[p];
            const float dot = __fmaf_rn(qz, dp.z, __fmaf_rn(qy, dp.y, __fmul_rn(qx, dp.x)));
            const float sq  = __fsub_rn(__fadd_rn(q2, dp.w), __fadd_rn(dot, dot));
            const float key = fmaxf(sq, 0.0f);
            if (key < cur_maxk) {
                int mp = 0; float m = -1.0f;
                for (int j = 0; j < KK; ++j) if (arrk[j] > m) { m = arrk[j]; mp = j; }
                arrk[mp] = key; arri[mp] = t0 + p;
                m = -1.0f;
                for (int j = 0; j < KK; ++j) if (arrk[j] > m) m = arrk[j];
                cur_maxk = m;
            }
        }
        __syncthreads();
    }
    const float kdist = sqrtf(cur_maxk);
    int acc[KNB]; int c = 0;
    for (int j = 0; j < KK; ++j) {
        const float d = sqrtf(arrk[j]);
        if (d < kdist && c < KNB) acc[c++] = arri[j];
    }
    for (int a = 1; a < c; ++a) {
        const int v = acc[a]; int j = a;
        while (j > 0 && acc[j-1] > v) { acc[j] = acc[j-1]; --j; }
        acc[j] = v;
    }
    int* row = out_nb + (size_t)q * KNB;
    for (int j = 0; j < KNB; ++j) row[j] = (j < c) ? acc[j] : ND;
    splits[1 + q] = c;
}

// --- K2: in-place scan of counts -> splits (single block) ---
__global__ __launch_bounds__(1024) void splits_scan_kernel(int* __restrict__ splits) {
    __shared__ int lds[1024];
    const int t = threadIdx.x;
    int v[16]; int s = 0;
    #pragma unroll
    for (int j = 0; j < 16; ++j) { v[j] = splits[1 + t*16 + j]; s += v[j]; }
    lds[t] = s;
    __syncthreads();
    for (int off = 1; off < 1024; off *= 2) {
        const int add = (t >= off) ? lds[t - off] : 0;
        __syncthreads();
        lds[t] += add;
        __syncthreads();
    }
    int run = lds[t] - s;
    #pragma unroll
    for (int j = 0; j < 16; ++j) { run += v[j]; splits[1 + t*16 + j] = run; }
    if (t == 0) splits[0] = 0;
}

extern "C" void kernel_launch(void* const* d_in, const int* in_sizes, int n_in,
                              void* d_out, int out_size, void* d_ws, size_t ws_size,
                              hipStream_t stream) {
    const float* data    = (const float*)d_in[0];
    const float* queries = (const float*)d_in[1];
    int* out    = (int*)d_out;
    int* splits = out + SPLITS_BASE;

    const size_t pts_bytes = (size_t)ND * sizeof(float4);   // 256 KB

    if (ws_size >= pts_bytes) {
        float4* pts = (float4*)d_ws;
        hipLaunchKernelGGL(build_pts, dim3(ND/256), dim3(256), 0, stream, data, pts);
        hipLaunchKernelGGL(knn_wave, dim3(NQ/NWQ), dim3(256), 0, stream,
                           pts, queries, out, splits);
    } else {
        hipLaunchKernelGGL(knn_direct_kernel, dim3(NQ/256), dim3(256), 0, stream,
                           data, queries, out, splits);
    }
    hipLaunchKernelGGL(splits_scan_kernel, dim3(1), dim3(1024), 0, stream, splits);
}